// Round 4
// baseline (776.605 us; speedup 1.0000x reference)
//
#include <hip/hip_runtime.h>
#include <hip/hip_bf16.h>

// LSTMFeatureExtractor: 2-layer LSTM (H=64, IN=1, B=2048, T=512) + FC(64->32)+ReLU
// R4: layer-split waves. 512-thread block, MB=8, grid 256 (1 block/CU, 2 waves/SIMD).
//     Waves 0-3 compute layer 0 (8 MFMA: Whh0), waves 4-7 layer 1 (16 MFMA:
//     Wih1+Whh1). Each wave owns 16 units x all 4 gates of its layer -> cell
//     update lane-local, no gate exchange, 1 barrier/iter. MFMA per CU halves
//     vs R3 (96 vs 192 for the same 8 batches); acts drop to 10/lane.
//     A-row replication (nq&7): batch b lands in D-reg b&3 on every quad;
//     quad -> batch-pair bb=(quad&1)*4+(quad&2), reg base j0=quad&2.
//     Loop runs k=0..512: L0 cells active k<512 (H0[1..512]), L1 cells k>=1
//     (H1[1..512]); uniform body, wx=0 for L1 folds the x-term to bias.

#define HID 64
#define TSTEPS 512
#define MB 8
#define RS 80   // f16 row stride: 160B = 40 words = 8 mod 32 -> <=2-way (free)

typedef _Float16 f16x8 __attribute__((ext_vector_type(8)));
typedef float f32x4 __attribute__((ext_vector_type(4)));

#define KSIG (-1.44269504089f)   // -log2(e)
#define KTANH (2.88539008178f)   // 2*log2(e)

__device__ __forceinline__ float fsig(float x) {
    return __builtin_amdgcn_rcpf(1.f + __builtin_amdgcn_exp2f(KSIG * x));
}
__device__ __forceinline__ float ftanh(float x) {
    return 1.f - 2.f * __builtin_amdgcn_rcpf(1.f + __builtin_amdgcn_exp2f(KTANH * x));
}

__global__ __launch_bounds__(512, 2) void lstm_feat_kernel(
    const float* __restrict__ x,
    const float* __restrict__ Wih0, const float* __restrict__ Whh0,
    const float* __restrict__ bih0, const float* __restrict__ bhh0,
    const float* __restrict__ Wih1, const float* __restrict__ Whh1,
    const float* __restrict__ bih1, const float* __restrict__ bhh1,
    const float* __restrict__ fcW, const float* __restrict__ fcb,
    float* __restrict__ out)
{
    __shared__ float x_lds[TSTEPS * MB];                   // [t][row], 16 KB
    __shared__ __align__(16) _Float16 h0_lds[2][MB * RS];
    __shared__ __align__(16) _Float16 h1_lds[2][MB * RS];
    __shared__ float h1f32[MB * HID];
    __shared__ float fcw_lds[32 * HID];
    __shared__ float fcb_lds[32];

    const int tid  = threadIdx.x;
    const int wave = tid >> 6;
    const bool wlow = wave < 4;          // layer-0 waves; waves 4-7: layer-1
    const int lane = tid & 63;
    const int nq   = lane & 15;
    const int quad = lane >> 4;
    const bool q2  = (quad & 2) != 0;
    const int bb   = (quad & 1) * 4 + (quad & 2);   // batch-pair base {0,4,2,6}
    const int bbase = blockIdx.x * MB;

    // ---- one-time staging ----
    for (int i = tid; i < TSTEPS * MB; i += 512) {
        int r = i >> 9, t = i & (TSTEPS - 1);
        x_lds[t * MB + r] = x[(bbase + r) * TSTEPS + t];   // coalesced in t
    }
    for (int i = tid; i < 32 * HID; i += 512) fcw_lds[i] = fcW[i];
    if (tid < 32) fcb_lds[tid] = fcb[tid];
    for (int i = tid; i < 2 * MB * RS; i += 512) {
        ((_Float16*)h0_lds)[i] = (_Float16)0.f;   // H0[0]=0 (both buffers)
        ((_Float16*)h1_lds)[i] = (_Float16)0.f;   // H1[0]=0 (both buffers)
    }

    // ---- per-lane weight fragments (B operand: lane holds W[n][k0..k0+8)) ----
    const int u16 = (wave & 3) * 16 + nq;   // unit owned within this layer
    const float* srcA = wlow ? Whh0 : Wih1;
    const float* srcB = wlow ? Whh0 : Whh1;  // dummy (unread) for L0 waves
    f16x8 wA[4][2], wB[4][2];
    float bv[4], wx[4];
    #pragma unroll
    for (int g = 0; g < 4; ++g) {
        const int n = g * 64 + u16;
        bv[g] = wlow ? (bih0[n] + bhh0[n]) : (bih1[n] + bhh1[n]);
        wx[g] = wlow ? Wih0[n] : 0.f;      // IN==1; L1: x-term folds away
        #pragma unroll
        for (int ks = 0; ks < 2; ++ks) {
            const int k0 = quad * 8 + ks * 32;
            f16x8 a, b;
            #pragma unroll
            for (int j = 0; j < 8; ++j) {
                a[j] = (_Float16)srcA[n * HID + k0 + j];
                b[j] = (_Float16)srcB[n * HID + k0 + j];
            }
            wA[g][ks] = a; wB[g][ks] = b;
        }
    }

    const f32x4 zero4 = {0.f, 0.f, 0.f, 0.f};
    const int arow = (nq & 7) * RS + quad * 8;   // A-replicated read offset
    float cst[2] = {0.f, 0.f};     // c-state for (bb, bb+1) of my layer
    float h1last[2] = {0.f, 0.f};

    __syncthreads();

    // ---- skewed recurrence, 513 iterations, 1 barrier each ----
    int p = 0;
    for (int k = 0; k <= TSTEPS; ++k) {
        const int q = p ^ 1;

        f16x8 a0[2];
        a0[0] = *(const f16x8*)&h0_lds[p][arow];
        a0[1] = *(const f16x8*)&h0_lds[p][arow + 32];

        f32x4 acc[4];
        #pragma unroll
        for (int g = 0; g < 4; ++g) {
            acc[g] = __builtin_amdgcn_mfma_f32_16x16x32_f16(a0[0], wA[g][0], zero4, 0, 0, 0);
            acc[g] = __builtin_amdgcn_mfma_f32_16x16x32_f16(a0[1], wA[g][1], acc[g], 0, 0, 0);
        }
        if (!wlow) {
            f16x8 a1[2];
            a1[0] = *(const f16x8*)&h1_lds[p][arow];
            a1[1] = *(const f16x8*)&h1_lds[p][arow + 32];
            #pragma unroll
            for (int g = 0; g < 4; ++g) {
                acc[g] = __builtin_amdgcn_mfma_f32_16x16x32_f16(a1[0], wB[g][0], acc[g], 0, 0, 0);
                acc[g] = __builtin_amdgcn_mfma_f32_16x16x32_f16(a1[1], wB[g][1], acc[g], 0, 0, 0);
            }
        }

        // L0 waves: cells for k=0..511 (-> H0[1..512]); L1: k=1..512 (-> H1[1..512])
        const bool docell = wlow ? (k < TSTEPS) : (k > 0);
        if (docell) {
            const int kx = (k < TSTEPS) ? k : 0;       // L1@512: wx=0, value unused
            const float2 xv = *(const float2*)&x_lds[kx * MB + bb];
            const float xj[2] = {xv.x, xv.y};
            _Float16* hdst = wlow ? h0_lds[q] : h1_lds[q];
            #pragma unroll
            for (int j = 0; j < 2; ++j) {
                const float vi = q2 ? acc[0][2 + j] : acc[0][j];
                const float vf = q2 ? acc[1][2 + j] : acc[1][j];
                const float vg = q2 ? acc[2][2 + j] : acc[2][j];
                const float vo = q2 ? acc[3][2 + j] : acc[3][j];
                const float pi = vi + fmaf(xj[j], wx[0], bv[0]);
                const float pf = vf + fmaf(xj[j], wx[1], bv[1]);
                const float pg = vg + fmaf(xj[j], wx[2], bv[2]);
                const float po = vo + fmaf(xj[j], wx[3], bv[3]);
                const float iv = fsig(pi), fv = fsig(pf), gv = ftanh(pg), ov = fsig(po);
                cst[j] = fv * cst[j] + iv * gv;
                const float h = ov * ftanh(cst[j]);
                h1last[j] = h;                          // meaningful on L1 waves
                hdst[(bb + j) * RS + u16] = (_Float16)h;
            }
        }
        p = q;
        __syncthreads();
    }

    // ---- epilogue: features = relu(H1[512] @ fcW^T + fcb) ----
    if (!wlow) {
        h1f32[(bb + 0) * HID + u16] = h1last[0];
        h1f32[(bb + 1) * HID + u16] = h1last[1];
    }
    __syncthreads();

    if (tid < MB * 32) {
        const int o  = tid & 31;
        const int rr = tid >> 5;
        float acc = fcb_lds[o];
        #pragma unroll 8
        for (int kk = 0; kk < HID; ++kk)
            acc += h1f32[rr * HID + kk] * fcw_lds[o * HID + kk];
        out[(bbase + rr) * 32 + o] = fmaxf(acc, 0.f);
    }
}

extern "C" void kernel_launch(void* const* d_in, const int* in_sizes, int n_in,
                              void* d_out, int out_size, void* d_ws, size_t ws_size,
                              hipStream_t stream) {
    const float* x    = (const float*)d_in[0];
    const float* Wih0 = (const float*)d_in[1];
    const float* Whh0 = (const float*)d_in[2];
    const float* bih0 = (const float*)d_in[3];
    const float* bhh0 = (const float*)d_in[4];
    const float* Wih1 = (const float*)d_in[5];
    const float* Whh1 = (const float*)d_in[6];
    const float* bih1 = (const float*)d_in[7];
    const float* bhh1 = (const float*)d_in[8];
    const float* fcW  = (const float*)d_in[9];
    const float* fcb  = (const float*)d_in[10];
    float* out = (float*)d_out;

    lstm_feat_kernel<<<2048 / MB, 512, 0, stream>>>(
        x, Wih0, Whh0, bih0, bhh0, Wih1, Whh1, bih1, bhh1, fcW, fcb, out);
}

// Round 5
// 408.961 us; speedup vs baseline: 1.8990x; 1.8990x over previous
//
#include <hip/hip_runtime.h>
#include <hip/hip_bf16.h>

// LSTMFeatureExtractor: 2-layer LSTM (H=64, IN=1, B=2048, T=512) + FC(64->32)+ReLU
// R5 = R3 skeleton (MB=4, grid 512, 256 thr, 2 independent blocks/CU) +
//  (a) zero-select batch mapping: A-row (nq>>2) puts batch=quad in ALL FOUR
//      D-regs of each quad -> cell math uses acc[g][0], no cndmask selects.
//  (b) anti-phase: the second resident block per CU (blockIdx>=256) does a
//      one-time ~1000-cy s_sleep so its MFMA burst overlaps the partner
//      block's VALU/trans burst (R3 showed VALU+MFMA == iter, i.e. zero
//      overlap from in-phase barrier locking).

#define HID 64
#define TSTEPS 512
#define MB 4
#define RS 80   // f16 row stride: 160B = 40 words = 8 mod 32 -> <=2-way (free)

typedef _Float16 f16x8 __attribute__((ext_vector_type(8)));
typedef float f32x4 __attribute__((ext_vector_type(4)));

#define KSIG (-1.44269504089f)   // -log2(e)
#define KTANH (2.88539008178f)   // 2*log2(e)

__device__ __forceinline__ float fsig(float x) {
    return __builtin_amdgcn_rcpf(1.f + __builtin_amdgcn_exp2f(KSIG * x));
}
__device__ __forceinline__ float ftanh(float x) {
    return 1.f - 2.f * __builtin_amdgcn_rcpf(1.f + __builtin_amdgcn_exp2f(KTANH * x));
}

__global__ __launch_bounds__(256, 2) void lstm_feat_kernel(
    const float* __restrict__ x,
    const float* __restrict__ Wih0, const float* __restrict__ Whh0,
    const float* __restrict__ bih0, const float* __restrict__ bhh0,
    const float* __restrict__ Wih1, const float* __restrict__ Whh1,
    const float* __restrict__ bih1, const float* __restrict__ bhh1,
    const float* __restrict__ fcW, const float* __restrict__ fcb,
    float* __restrict__ out)
{
    __shared__ float x_lds[TSTEPS * MB];                   // [t][row], 8 KB
    __shared__ __align__(16) _Float16 h0_lds[2][MB * RS];
    __shared__ __align__(16) _Float16 h1_lds[2][MB * RS];
    __shared__ float h1f32[MB * HID];
    __shared__ float fcw_lds[32 * HID];
    __shared__ float fcb_lds[32];

    const int tid  = threadIdx.x;
    const int wave = tid >> 6;
    const int lane = tid & 63;
    const int nq   = lane & 15;
    const int quad = lane >> 4;     // this lane's batch row
    const int bbase = blockIdx.x * MB;

    // ---- one-time staging ----
    for (int i = tid; i < TSTEPS * MB; i += 256) {
        int r = i >> 9, t = i & (TSTEPS - 1);
        x_lds[t * MB + r] = x[(bbase + r) * TSTEPS + t];   // coalesced in t
    }
    for (int i = tid; i < 32 * HID; i += 256) fcw_lds[i] = fcW[i];
    if (tid < 32) fcb_lds[tid] = fcb[tid];
    for (int i = tid; i < 2 * MB * RS; i += 256) {
        ((_Float16*)h0_lds)[i] = (_Float16)0.f;            // H0[0]=0 (both bufs)
        ((_Float16*)h1_lds)[i] = (_Float16)0.f;            // H1[0]=0 (both bufs)
    }

    // ---- per-lane weight fragments (B operand: lane holds W[n][k0..k0+8)) ----
    const int u = wave * 16 + nq;   // unit owned
    f16x8 w0[4][2], wi1[4][2], wh1[4][2];
    float b0v[4], b1v[4], wx0[4];
    #pragma unroll
    for (int g = 0; g < 4; ++g) {
        const int n = g * 64 + u;
        b0v[g] = bih0[n] + bhh0[n];
        b1v[g] = bih1[n] + bhh1[n];
        wx0[g] = Wih0[n];           // IN==1
        #pragma unroll
        for (int ks = 0; ks < 2; ++ks) {
            const int k0 = quad * 8 + ks * 32;
            f16x8 a, b, c;
            #pragma unroll
            for (int j = 0; j < 8; ++j) {
                a[j] = (_Float16)Whh0[n * HID + k0 + j];
                b[j] = (_Float16)Wih1[n * HID + k0 + j];
                c[j] = (_Float16)Whh1[n * HID + k0 + j];
            }
            w0[g][ks] = a; wi1[g][ks] = b; wh1[g][ks] = c;
        }
    }

    const f32x4 zero4 = {0.f, 0.f, 0.f, 0.f};
    // A-row (nq>>2): A row m carries h[batch m/4] => D row quad*4+r = batch quad
    // for every r -> use acc[g][0] directly, zero selects.
    const int arow = (nq >> 2) * RS + quad * 8;
    float c0 = 0.f, c1 = 0.f;

    __syncthreads();

    // Anti-phase: second resident block per CU starts ~1000 cy late (one-time).
    if (blockIdx.x >= 256) {
        __builtin_amdgcn_s_sleep(8);
        __builtin_amdgcn_s_sleep(8);
    }

    // ---- skewed recurrence: iter k makes H0[k+1] (x[k],H0[k]) and H1[k]
    //      (H0[k],H1[k-1]); single barrier; 512 even iterations ----
    int p = 0;
    for (int k = 0; k < TSTEPS; ++k) {
        const int q = p ^ 1;

        f16x8 a0[2], a1[2];
        a0[0] = *(const f16x8*)&h0_lds[p][arow];
        a0[1] = *(const f16x8*)&h0_lds[p][arow + 32];
        a1[0] = *(const f16x8*)&h1_lds[p][arow];
        a1[1] = *(const f16x8*)&h1_lds[p][arow + 32];
        const float xq = x_lds[k * MB + quad];   // this lane's batch row = quad

        f32x4 acc0[4], acc1[4];
        #pragma unroll
        for (int g = 0; g < 4; ++g) {
            acc0[g] = __builtin_amdgcn_mfma_f32_16x16x32_f16(a0[0], w0[g][0], zero4, 0, 0, 0);
            acc0[g] = __builtin_amdgcn_mfma_f32_16x16x32_f16(a0[1], w0[g][1], acc0[g], 0, 0, 0);
        }
        #pragma unroll
        for (int g = 0; g < 4; ++g) {
            acc1[g] = __builtin_amdgcn_mfma_f32_16x16x32_f16(a0[0], wi1[g][0], zero4, 0, 0, 0);
            acc1[g] = __builtin_amdgcn_mfma_f32_16x16x32_f16(a0[1], wi1[g][1], acc1[g], 0, 0, 0);
            acc1[g] = __builtin_amdgcn_mfma_f32_16x16x32_f16(a1[0], wh1[g][0], acc1[g], 0, 0, 0);
            acc1[g] = __builtin_amdgcn_mfma_f32_16x16x32_f16(a1[1], wh1[g][1], acc1[g], 0, 0, 0);
        }

        // layer0 cell for batch row = quad (reg 0 holds it on every quad)
        {
            const float pi = acc0[0][0] + fmaf(xq, wx0[0], b0v[0]);
            const float pf = acc0[1][0] + fmaf(xq, wx0[1], b0v[1]);
            const float pg = acc0[2][0] + fmaf(xq, wx0[2], b0v[2]);
            const float po = acc0[3][0] + fmaf(xq, wx0[3], b0v[3]);
            const float iv = fsig(pi), fv = fsig(pf), gv = ftanh(pg), ov = fsig(po);
            c0 = fv * c0 + iv * gv;
            h0_lds[q][quad * RS + u] = (_Float16)(ov * ftanh(c0));
        }
        // layer1 cell -> H1[k]; skip k==0 (buffers pre-zeroed = H1[0])
        if (k > 0) {
            const float pi = acc1[0][0] + b1v[0];
            const float pf = acc1[1][0] + b1v[1];
            const float pg = acc1[2][0] + b1v[2];
            const float po = acc1[3][0] + b1v[3];
            const float iv = fsig(pi), fv = fsig(pf), gv = ftanh(pg), ov = fsig(po);
            c1 = fv * c1 + iv * gv;
            h1_lds[q][quad * RS + u] = (_Float16)(ov * ftanh(c1));
        }
        p = q;
        __syncthreads();
    }

    // ---- peeled final layer-1 step: H1[512] from H0[512], H1[511] ----
    float h1last;
    {
        f16x8 a0f[2], a1f[2];
        a0f[0] = *(const f16x8*)&h0_lds[p][arow];
        a0f[1] = *(const f16x8*)&h0_lds[p][arow + 32];
        a1f[0] = *(const f16x8*)&h1_lds[p][arow];
        a1f[1] = *(const f16x8*)&h1_lds[p][arow + 32];
        f32x4 acc1[4];
        #pragma unroll
        for (int g = 0; g < 4; ++g) {
            acc1[g] = __builtin_amdgcn_mfma_f32_16x16x32_f16(a0f[0], wi1[g][0], zero4, 0, 0, 0);
            acc1[g] = __builtin_amdgcn_mfma_f32_16x16x32_f16(a0f[1], wi1[g][1], acc1[g], 0, 0, 0);
            acc1[g] = __builtin_amdgcn_mfma_f32_16x16x32_f16(a1f[0], wh1[g][0], acc1[g], 0, 0, 0);
            acc1[g] = __builtin_amdgcn_mfma_f32_16x16x32_f16(a1f[1], wh1[g][1], acc1[g], 0, 0, 0);
        }
        const float pi = acc1[0][0] + b1v[0];
        const float pf = acc1[1][0] + b1v[1];
        const float pg = acc1[2][0] + b1v[2];
        const float po = acc1[3][0] + b1v[3];
        const float iv = fsig(pi), fv = fsig(pf), gv = ftanh(pg), ov = fsig(po);
        c1 = fv * c1 + iv * gv;
        h1last = ov * ftanh(c1);
    }

    // ---- epilogue: features = relu(H1[512] @ fcW^T + fcb) ----
    h1f32[quad * HID + u] = h1last;   // each lane: 1 value (row=quad, unit=u)
    __syncthreads();

    if (tid < MB * 32) {
        const int o  = tid & 31;
        const int rr = tid >> 5;
        float acc = fcb_lds[o];
        #pragma unroll 8
        for (int kk = 0; kk < HID; ++kk)
            acc += h1f32[rr * HID + kk] * fcw_lds[o * HID + kk];
        out[(bbase + rr) * 32 + o] = fmaxf(acc, 0.f);
    }
}

extern "C" void kernel_launch(void* const* d_in, const int* in_sizes, int n_in,
                              void* d_out, int out_size, void* d_ws, size_t ws_size,
                              hipStream_t stream) {
    const float* x    = (const float*)d_in[0];
    const float* Wih0 = (const float*)d_in[1];
    const float* Whh0 = (const float*)d_in[2];
    const float* bih0 = (const float*)d_in[3];
    const float* bhh0 = (const float*)d_in[4];
    const float* Wih1 = (const float*)d_in[5];
    const float* Whh1 = (const float*)d_in[6];
    const float* bih1 = (const float*)d_in[7];
    const float* bhh1 = (const float*)d_in[8];
    const float* fcW  = (const float*)d_in[9];
    const float* fcb  = (const float*)d_in[10];
    float* out = (float*)d_out;

    lstm_feat_kernel<<<2048 / MB, 256, 0, stream>>>(
        x, Wih0, Whh0, bih0, bhh0, Wih1, Whh1, bih1, bhh1, fcW, fcb, out);
}

// Round 6
// 374.748 us; speedup vs baseline: 2.0723x; 1.0913x over previous
//
#include <hip/hip_runtime.h>
#include <hip/hip_bf16.h>

// LSTMFeatureExtractor: 2-layer LSTM (H=64, IN=1, B=2048, T=512) + FC(64->32)+ReLU
// R6 = R5 + MFMA dependency-chain surgery. R5 counters showed ~18 cy/MFMA of
// pipe occupancy (latency, not the 4.85-cy throughput): gate-major emission
// put dependent MFMAs back-to-back, and L1 was a 4-deep chain per gate.
// Fix: (a) split L1 into two independent 2-chains (accA=h0@Wih1, accB=h1@Whh1,
// fp32 add at the end); (b) K-major emission: 12 independent C=0 MFMAs first,
// then 12 second-links each ~58 cy behind their producer. MFMA becomes
// issue-bound (~117 cy/wave/iter).

#define HID 64
#define TSTEPS 512
#define MB 4
#define RS 80   // f16 row stride: 160B = 40 words = 8 mod 32 -> <=2-way (free)

typedef _Float16 f16x8 __attribute__((ext_vector_type(8)));
typedef float f32x4 __attribute__((ext_vector_type(4)));

#define KSIG (-1.44269504089f)   // -log2(e)
#define KTANH (2.88539008178f)   // 2*log2(e)

__device__ __forceinline__ float fsig(float x) {
    return __builtin_amdgcn_rcpf(1.f + __builtin_amdgcn_exp2f(KSIG * x));
}
__device__ __forceinline__ float ftanh(float x) {
    return 1.f - 2.f * __builtin_amdgcn_rcpf(1.f + __builtin_amdgcn_exp2f(KTANH * x));
}

__global__ __launch_bounds__(256, 2) void lstm_feat_kernel(
    const float* __restrict__ x,
    const float* __restrict__ Wih0, const float* __restrict__ Whh0,
    const float* __restrict__ bih0, const float* __restrict__ bhh0,
    const float* __restrict__ Wih1, const float* __restrict__ Whh1,
    const float* __restrict__ bih1, const float* __restrict__ bhh1,
    const float* __restrict__ fcW, const float* __restrict__ fcb,
    float* __restrict__ out)
{
    __shared__ float x_lds[TSTEPS * MB];                   // [t][row], 8 KB
    __shared__ __align__(16) _Float16 h0_lds[2][MB * RS];
    __shared__ __align__(16) _Float16 h1_lds[2][MB * RS];
    __shared__ float h1f32[MB * HID];
    __shared__ float fcw_lds[32 * HID];
    __shared__ float fcb_lds[32];

    const int tid  = threadIdx.x;
    const int wave = tid >> 6;
    const int lane = tid & 63;
    const int nq   = lane & 15;
    const int quad = lane >> 4;     // this lane's batch row
    const int bbase = blockIdx.x * MB;

    // ---- one-time staging ----
    for (int i = tid; i < TSTEPS * MB; i += 256) {
        int r = i >> 9, t = i & (TSTEPS - 1);
        x_lds[t * MB + r] = x[(bbase + r) * TSTEPS + t];   // coalesced in t
    }
    for (int i = tid; i < 32 * HID; i += 256) fcw_lds[i] = fcW[i];
    if (tid < 32) fcb_lds[tid] = fcb[tid];
    for (int i = tid; i < 2 * MB * RS; i += 256) {
        ((_Float16*)h0_lds)[i] = (_Float16)0.f;            // H0[0]=0 (both bufs)
        ((_Float16*)h1_lds)[i] = (_Float16)0.f;            // H1[0]=0 (both bufs)
    }

    // ---- per-lane weight fragments (B operand: lane holds W[n][k0..k0+8)) ----
    const int u = wave * 16 + nq;   // unit owned
    f16x8 w0[4][2], wi1[4][2], wh1[4][2];
    float b0v[4], b1v[4], wx0[4];
    #pragma unroll
    for (int g = 0; g < 4; ++g) {
        const int n = g * 64 + u;
        b0v[g] = bih0[n] + bhh0[n];
        b1v[g] = bih1[n] + bhh1[n];
        wx0[g] = Wih0[n];           // IN==1
        #pragma unroll
        for (int ks = 0; ks < 2; ++ks) {
            const int k0 = quad * 8 + ks * 32;
            f16x8 a, b, c;
            #pragma unroll
            for (int j = 0; j < 8; ++j) {
                a[j] = (_Float16)Whh0[n * HID + k0 + j];
                b[j] = (_Float16)Wih1[n * HID + k0 + j];
                c[j] = (_Float16)Whh1[n * HID + k0 + j];
            }
            w0[g][ks] = a; wi1[g][ks] = b; wh1[g][ks] = c;
        }
    }

    const f32x4 zero4 = {0.f, 0.f, 0.f, 0.f};
    // A-row (nq>>2): A row m carries h[batch m/4] => D row quad*4+r = batch quad
    // for every r -> use element [0] directly, zero selects.
    const int arow = (nq >> 2) * RS + quad * 8;
    float c0 = 0.f, c1 = 0.f;

    __syncthreads();

    // Anti-phase: second resident block per CU starts ~1000 cy late (one-time).
    if (blockIdx.x >= 256) {
        __builtin_amdgcn_s_sleep(8);
        __builtin_amdgcn_s_sleep(8);
    }

    // ---- skewed recurrence: iter k makes H0[k+1] (x[k],H0[k]) and H1[k]
    //      (H0[k],H1[k-1]); single barrier; 512 even iterations ----
    int p = 0;
    for (int k = 0; k < TSTEPS; ++k) {
        const int q = p ^ 1;

        f16x8 a0[2], a1[2];
        a0[0] = *(const f16x8*)&h0_lds[p][arow];
        a0[1] = *(const f16x8*)&h0_lds[p][arow + 32];
        a1[0] = *(const f16x8*)&h1_lds[p][arow];
        a1[1] = *(const f16x8*)&h1_lds[p][arow + 32];
        const float xq = x_lds[k * MB + quad];   // this lane's batch row = quad

        // K-major, chains of depth 2 only: 12 independent C=0 MFMAs, then the
        // 12 second links (each ~12 issues behind its producer).
        f32x4 acc0[4], accA[4], accB[4];
        #pragma unroll
        for (int g = 0; g < 4; ++g)
            acc0[g] = __builtin_amdgcn_mfma_f32_16x16x32_f16(a0[0], w0[g][0], zero4, 0, 0, 0);
        #pragma unroll
        for (int g = 0; g < 4; ++g)
            accA[g] = __builtin_amdgcn_mfma_f32_16x16x32_f16(a0[0], wi1[g][0], zero4, 0, 0, 0);
        #pragma unroll
        for (int g = 0; g < 4; ++g)
            accB[g] = __builtin_amdgcn_mfma_f32_16x16x32_f16(a1[0], wh1[g][0], zero4, 0, 0, 0);
        #pragma unroll
        for (int g = 0; g < 4; ++g)
            acc0[g] = __builtin_amdgcn_mfma_f32_16x16x32_f16(a0[1], w0[g][1], acc0[g], 0, 0, 0);
        #pragma unroll
        for (int g = 0; g < 4; ++g)
            accA[g] = __builtin_amdgcn_mfma_f32_16x16x32_f16(a0[1], wi1[g][1], accA[g], 0, 0, 0);
        #pragma unroll
        for (int g = 0; g < 4; ++g)
            accB[g] = __builtin_amdgcn_mfma_f32_16x16x32_f16(a1[1], wh1[g][1], accB[g], 0, 0, 0);

        // layer0 cell for batch row = quad (element 0 on every quad)
        {
            const float pi = acc0[0][0] + fmaf(xq, wx0[0], b0v[0]);
            const float pf = acc0[1][0] + fmaf(xq, wx0[1], b0v[1]);
            const float pg = acc0[2][0] + fmaf(xq, wx0[2], b0v[2]);
            const float po = acc0[3][0] + fmaf(xq, wx0[3], b0v[3]);
            const float iv = fsig(pi), fv = fsig(pf), gv = ftanh(pg), ov = fsig(po);
            c0 = fv * c0 + iv * gv;
            h0_lds[q][quad * RS + u] = (_Float16)(ov * ftanh(c0));
        }
        // layer1 cell -> H1[k]; skip k==0 (buffers pre-zeroed = H1[0])
        if (k > 0) {
            const float pi = accA[0][0] + accB[0][0] + b1v[0];
            const float pf = accA[1][0] + accB[1][0] + b1v[1];
            const float pg = accA[2][0] + accB[2][0] + b1v[2];
            const float po = accA[3][0] + accB[3][0] + b1v[3];
            const float iv = fsig(pi), fv = fsig(pf), gv = ftanh(pg), ov = fsig(po);
            c1 = fv * c1 + iv * gv;
            h1_lds[q][quad * RS + u] = (_Float16)(ov * ftanh(c1));
        }
        p = q;
        __syncthreads();
    }

    // ---- peeled final layer-1 step: H1[512] from H0[512], H1[511] ----
    float h1last;
    {
        f16x8 a0f[2], a1f[2];
        a0f[0] = *(const f16x8*)&h0_lds[p][arow];
        a0f[1] = *(const f16x8*)&h0_lds[p][arow + 32];
        a1f[0] = *(const f16x8*)&h1_lds[p][arow];
        a1f[1] = *(const f16x8*)&h1_lds[p][arow + 32];
        f32x4 accA[4], accB[4];
        #pragma unroll
        for (int g = 0; g < 4; ++g)
            accA[g] = __builtin_amdgcn_mfma_f32_16x16x32_f16(a0f[0], wi1[g][0], zero4, 0, 0, 0);
        #pragma unroll
        for (int g = 0; g < 4; ++g)
            accB[g] = __builtin_amdgcn_mfma_f32_16x16x32_f16(a1f[0], wh1[g][0], zero4, 0, 0, 0);
        #pragma unroll
        for (int g = 0; g < 4; ++g)
            accA[g] = __builtin_amdgcn_mfma_f32_16x16x32_f16(a0f[1], wi1[g][1], accA[g], 0, 0, 0);
        #pragma unroll
        for (int g = 0; g < 4; ++g)
            accB[g] = __builtin_amdgcn_mfma_f32_16x16x32_f16(a1f[1], wh1[g][1], accB[g], 0, 0, 0);
        const float pi = accA[0][0] + accB[0][0] + b1v[0];
        const float pf = accA[1][0] + accB[1][0] + b1v[1];
        const float pg = accA[2][0] + accB[2][0] + b1v[2];
        const float po = accA[3][0] + accB[3][0] + b1v[3];
        const float iv = fsig(pi), fv = fsig(pf), gv = ftanh(pg), ov = fsig(po);
        c1 = fv * c1 + iv * gv;
        h1last = ov * ftanh(c1);
    }

    // ---- epilogue: features = relu(H1[512] @ fcW^T + fcb) ----
    h1f32[quad * HID + u] = h1last;   // each lane: 1 value (row=quad, unit=u)
    __syncthreads();

    if (tid < MB * 32) {
        const int o  = tid & 31;
        const int rr = tid >> 5;
        float acc = fcb_lds[o];
        #pragma unroll 8
        for (int kk = 0; kk < HID; ++kk)
            acc += h1f32[rr * HID + kk] * fcw_lds[o * HID + kk];
        out[(bbase + rr) * 32 + o] = fmaxf(acc, 0.f);
    }
}

extern "C" void kernel_launch(void* const* d_in, const int* in_sizes, int n_in,
                              void* d_out, int out_size, void* d_ws, size_t ws_size,
                              hipStream_t stream) {
    const float* x    = (const float*)d_in[0];
    const float* Wih0 = (const float*)d_in[1];
    const float* Whh0 = (const float*)d_in[2];
    const float* bih0 = (const float*)d_in[3];
    const float* bhh0 = (const float*)d_in[4];
    const float* Wih1 = (const float*)d_in[5];
    const float* Whh1 = (const float*)d_in[6];
    const float* bih1 = (const float*)d_in[7];
    const float* bhh1 = (const float*)d_in[8];
    const float* fcW  = (const float*)d_in[9];
    const float* fcb  = (const float*)d_in[10];
    float* out = (float*)d_out;

    lstm_feat_kernel<<<2048 / MB, 256, 0, stream>>>(
        x, Wih0, Whh0, bih0, bhh0, Wih1, Whh1, bih1, bhh1, fcW, fcb, out);
}